// Round 2
// baseline (569.745 us; speedup 1.0000x reference)
//
#include <hip/hip_runtime.h>
#include <hip/hip_bf16.h>

// ---------------------------------------------------------------------------
// Spatial_AttLayer on MI355X (gfx950) — round 2.
// Key changes vs round 1:
//  * k_main: 64 cols/block (2 t), LDS 75.8 KB -> 2 blocks/CU, 4 barriers total.
//    All-head Z materialized in LDS (wave=head), single K=512 GEMM3 with Wo
//    read straight from global (L2-resident bf16 copy). Fl overlaps Za region.
//  * Pre-kernels rewritten: wave-per-row q/k conv (scalar weight loads),
//    parallel energy pairs in k_attn.
// ---------------------------------------------------------------------------

typedef __attribute__((ext_vector_type(8))) short short8;
typedef __attribute__((ext_vector_type(4))) short short4v;
typedef __attribute__((ext_vector_type(4))) float f4v;

static __device__ __forceinline__ unsigned short f2bf(float f) {
  union { float f; unsigned u; } v; v.f = f;
  unsigned r = v.u + 0x7fffu + ((v.u >> 16) & 1u);   // RNE
  return (unsigned short)(r >> 16);
}
static __device__ __forceinline__ float bf2f(unsigned short h) {
  union { unsigned u; float f; } v; v.u = ((unsigned)h) << 16;
  return v.f;
}

// ws layout: WvP [64][256] bf16 | WoP [256][512] bf16 | attnP [8][32][40] bf16
//            | qkP [1024][25] f32   (q rows 0..511, k rows 512..1023)

// ---------------------------------------------------------------------------
// k_pre: blocks 0..255: q/k rows (1 row/wave, 4 waves/block).
//        blocks 256..287: Wo -> bf16.  blocks 288..289: Wv -> bf16.
__global__ void k_pre(const float* __restrict__ tf,
                      const float* __restrict__ Wq, const float* __restrict__ bq,
                      const float* __restrict__ Wk, const float* __restrict__ bk,
                      const float* __restrict__ Wv, const float* __restrict__ Wo,
                      unsigned short* __restrict__ WvP,
                      unsigned short* __restrict__ WoP,
                      float* __restrict__ qkP)
{
  const int bx = blockIdx.x, tid = threadIdx.x;
  if (bx < 256) {
    const int r = __builtin_amdgcn_readfirstlane(bx * 4 + (tid >> 6));
    const int u = tid & 63;
    const int u2 = (u < 25) ? u : 24;          // keep OOB lanes in-bounds
    const int isK = r >= 512, g = r & 511;
    const float* W = (isK ? Wk : Wq) + g * 512;
    float s0 = 0.f, s1 = 0.f, s2 = 0.f, s3 = 0.f;
    #pragma unroll 4
    for (int i = 0; i < 512; i += 4) {
      s0 += W[i + 0] * tf[(i + 0) * 25 + u2];
      s1 += W[i + 1] * tf[(i + 1) * 25 + u2];
      s2 += W[i + 2] * tf[(i + 2) * 25 + u2];
      s3 += W[i + 3] * tf[(i + 3) * 25 + u2];
    }
    float s = ((s0 + s1) + (s2 + s3)) + (isK ? bk : bq)[g];
    if (u < 25) qkP[r * 25 + u] = s;
  } else if (bx < 288) {
    // Wo: 131072 elems = 32768 float4
    const float4* W4 = reinterpret_cast<const float4*>(Wo);
    short4v* D4 = reinterpret_cast<short4v*>(WoP);
    int base = (bx - 256) * 256 + tid;
    #pragma unroll
    for (int e = 0; e < 4; ++e) {
      int i4 = base + e * 8192;
      float4 f = W4[i4];
      short4v s = {(short)f2bf(f.x), (short)f2bf(f.y), (short)f2bf(f.z), (short)f2bf(f.w)};
      D4[i4] = s;
    }
  } else {
    // Wv: 16384 elems = 4096 float4
    const float4* W4 = reinterpret_cast<const float4*>(Wv);
    short4v* D4 = reinterpret_cast<short4v*>(WvP);
    int base = (bx - 288) * 256 + tid;
    #pragma unroll
    for (int e = 0; e < 8; ++e) {
      int i4 = base + e * 512;
      float4 f = W4[i4];
      short4v s = {(short)f2bf(f.x), (short)f2bf(f.y), (short)f2bf(f.z), (short)f2bf(f.w)};
      D4[i4] = s;
    }
  }
}

// ---------------------------------------------------------------------------
// k_attn: block = head. energy (625 pairs parallel) + softmax -> attnP padded.
__global__ void k_attn(const float* __restrict__ qkP,
                       unsigned short* __restrict__ attnP)
{
  __shared__ float ql[1600], kl[1600], el[625];
  const int h = blockIdx.x, tid = threadIdx.x;
  for (int i = tid; i < 1600; i += 256) {
    ql[i] = qkP[h * 1600 + i];
    kl[i] = qkP[12800 + h * 1600 + i];
  }
  __syncthreads();
  for (int p = tid; p < 625; p += 256) {
    int u = p / 25, v = p - 25 * u;
    float s = 0.f;
    #pragma unroll 16
    for (int c = 0; c < 64; ++c) s += ql[c * 25 + u] * kl[c * 25 + v];
    el[p] = s * 0.125f;                       // 1/sqrt(64)
  }
  __syncthreads();
  if (tid < 25) {
    const int u = tid;
    float mx = -1e30f;
    #pragma unroll
    for (int v = 0; v < 25; ++v) mx = fmaxf(mx, el[u * 25 + v]);
    float den = 0.f;
    float ex[25];
    #pragma unroll
    for (int v = 0; v < 25; ++v) { ex[v] = __expf(el[u * 25 + v] - mx); den += ex[v]; }
    float inv = 1.f / den;
    #pragma unroll
    for (int v = 0; v < 25; ++v) el[u * 25 + v] = ex[v] * inv;
  }
  __syncthreads();
  for (int i = tid; i < 1280; i += 256) {
    int vp = i / 40, uu = i - 40 * vp;
    attnP[h * 1280 + i] =
        (vp < 25 && uu < 25) ? f2bf(el[uu * 25 + vp]) : (unsigned short)0;
  }
}

// ---------------------------------------------------------------------------
// k_main: 4096 blocks (n=bx>>9, 2 t's), 512 threads, LDS 75776 B (2 blk/CU).
// LDS: region0 @0: Fl [64][264] (stage) then Za [64][520] (Z all heads)
//      Vl @66560: [64][72]
__launch_bounds__(512, 4)
__global__ void k_main(const float* __restrict__ feature,
                       const float* __restrict__ bv,
                       const float* __restrict__ bo,
                       const unsigned short* __restrict__ WvP,
                       const unsigned short* __restrict__ WoP,
                       const unsigned short* __restrict__ attnP,
                       float* __restrict__ out)
{
  extern __shared__ char smem[];
  unsigned short* Fl = (unsigned short*)smem;            // [64][264]
  unsigned short* Za = (unsigned short*)smem;            // [64][520] (after Fl dead)
  unsigned short* Vl = (unsigned short*)(smem + 66560);  // [64][72]

  const int tid  = threadIdx.x;
  const int wave = tid >> 6;
  const int lane = tid & 63;
  const int quad = lane >> 4;
  const int l16  = lane & 15;
  const int n  = blockIdx.x >> 9;
  const int tb = blockIdx.x & 511;
  const int t0 = tb * 2;

  // --- stage F: fp32 -> bf16, Fl[col=t*32+vp][c]; zero vp pads ---
  {
    const int c = tid >> 1, p = tid & 1;
    const float2* src = reinterpret_cast<const float2*>(
        feature + ((size_t)(n * 256 + c) * 1024 + t0) * 25);
    for (int i = p; i < 25; i += 2) {
      float2 f = src[i];
      int j = 2 * i;
      int t = (j >= 25); int vp = j - 25 * t;
      Fl[(t * 32 + vp) * 264 + c] = f2bf(f.x);
      ++j; t = (j >= 25); vp = j - 25 * t;
      Fl[(t * 32 + vp) * 264 + c] = f2bf(f.y);
    }
    #pragma unroll
    for (int z = p; z < 14; z += 2) {
      int t = (z >= 7); int vp = 25 + z - 7 * t;
      Fl[(t * 32 + vp) * 264 + c] = 0;
    }
  }
  __syncthreads();

  // --- GEMM1: Vm = Wv@F + bv. wave: mt=wave&3 (16 rows), nh=wave>>2 (32 cols)
  {
    const int mt = wave & 3, nh = wave >> 2;
    f4v accv[2];
    #pragma unroll
    for (int ni = 0; ni < 2; ++ni)
      #pragma unroll
      for (int r = 0; r < 4; ++r) accv[ni][r] = bv[mt * 16 + quad * 4 + r];
    #pragma unroll 2
    for (int ks = 0; ks < 8; ++ks) {
      short8 a = *reinterpret_cast<const short8*>(
          WvP + (mt * 16 + l16) * 256 + ks * 32 + quad * 8);
      #pragma unroll
      for (int ni = 0; ni < 2; ++ni) {
        short8 b = *reinterpret_cast<const short8*>(
            &Fl[(nh * 32 + ni * 16 + l16) * 264 + ks * 32 + quad * 8]);
        accv[ni] = __builtin_amdgcn_mfma_f32_16x16x32_bf16(a, b, accv[ni], 0, 0, 0);
      }
    }
    #pragma unroll
    for (int ni = 0; ni < 2; ++ni)
      #pragma unroll
      for (int r = 0; r < 4; ++r)
        Vl[(mt * 16 + quad * 4 + r) * 72 + nh * 32 + ni * 16 + l16] =
            f2bf(accv[ni][r]);
  }

  // --- GEMM3 accumulators: bias + residual (reads Fl before it dies) ---
  f4v acc[2][4];
  #pragma unroll
  for (int mi = 0; mi < 2; ++mi) {
    #pragma unroll
    for (int r = 0; r < 4; ++r) {
      int o = wave * 32 + mi * 16 + quad * 4 + r;
      float bor = bo[o];
      #pragma unroll
      for (int ni = 0; ni < 4; ++ni)
        acc[mi][ni][r] = bor + bf2f(Fl[(ni * 16 + l16) * 264 + o]);
    }
  }
  __syncthreads();   // Fl reads & Vl writes complete

  // --- GEMM2: wave = head h. Zh = Vm @ attn[h] -> Za[col][h*64+c] ---
  {
    const int h = wave;
    short8 bfr2[2];
    bfr2[0] = *reinterpret_cast<const short8*>(attnP + h * 1280 + l16 * 40 + quad * 8);
    bfr2[1] = *reinterpret_cast<const short8*>(attnP + h * 1280 + (16 + l16) * 40 + quad * 8);
    #pragma unroll
    for (int nt = 0; nt < 4; ++nt) {
      int t = nt >> 1, vh = nt & 1;
      #pragma unroll
      for (int mi = 0; mi < 4; ++mi) {
        f4v az = {0.f, 0.f, 0.f, 0.f};
        short8 a = *reinterpret_cast<const short8*>(
            &Vl[(mi * 16 + l16) * 72 + t * 32 + quad * 8]);
        az = __builtin_amdgcn_mfma_f32_16x16x32_bf16(a, bfr2[vh], az, 0, 0, 0);
        short4v pk = {(short)f2bf(az[0]), (short)f2bf(az[1]),
                      (short)f2bf(az[2]), (short)f2bf(az[3])};
        *reinterpret_cast<short4v*>(
            &Za[(nt * 16 + l16) * 520 + h * 64 + mi * 16 + quad * 4]) = pk;
      }
    }
  }
  __syncthreads();   // Za complete

  // --- GEMM3: acc += Wo @ Za, K=512, wave owns rows wave*32..+31 ---
  {
    const unsigned short* wbase = WoP + ((size_t)(wave * 32 + l16)) * 512;
    #pragma unroll 2
    for (int ks = 0; ks < 16; ++ks) {
      short8 a0 = *reinterpret_cast<const short8*>(wbase + ks * 32 + quad * 8);
      short8 a1 = *reinterpret_cast<const short8*>(wbase + 16 * 512 + ks * 32 + quad * 8);
      short8 b[4];
      #pragma unroll
      for (int ni = 0; ni < 4; ++ni)
        b[ni] = *reinterpret_cast<const short8*>(
            &Za[(ni * 16 + l16) * 520 + ks * 32 + quad * 8]);
      #pragma unroll
      for (int ni = 0; ni < 4; ++ni)
        acc[0][ni] = __builtin_amdgcn_mfma_f32_16x16x32_bf16(a0, b[ni], acc[0][ni], 0, 0, 0);
      #pragma unroll
      for (int ni = 0; ni < 4; ++ni)
        acc[1][ni] = __builtin_amdgcn_mfma_f32_16x16x32_bf16(a1, b[ni], acc[1][ni], 0, 0, 0);
    }
  }

  // --- epilogue ---
  #pragma unroll
  for (int ni = 0; ni < 4; ++ni) {
    int col = ni * 16 + l16;
    int t = col >> 5, vp = col & 31;
    if (vp < 25) {
      #pragma unroll
      for (int mi = 0; mi < 2; ++mi) {
        #pragma unroll
        for (int r = 0; r < 4; ++r) {
          int o = wave * 32 + mi * 16 + quad * 4 + r;
          out[((size_t)(n * 256 + o) * 1024 + (t0 + t)) * 25 + vp] = acc[mi][ni][r];
        }
      }
    }
  }
}

// ---------------------------------------------------------------------------
extern "C" void kernel_launch(void* const* d_in, const int* in_sizes, int n_in,
                              void* d_out, int out_size, void* d_ws, size_t ws_size,
                              hipStream_t stream)
{
  const float* feature = (const float*)d_in[0];
  const float* tf      = (const float*)d_in[1];
  const float* Wq      = (const float*)d_in[2];
  const float* bq      = (const float*)d_in[3];
  const float* Wk      = (const float*)d_in[4];
  const float* bk      = (const float*)d_in[5];
  const float* Wv      = (const float*)d_in[6];
  const float* bv      = (const float*)d_in[7];
  const float* Wo      = (const float*)d_in[8];
  const float* bo      = (const float*)d_in[9];
  float* out = (float*)d_out;

  unsigned short* WvP   = (unsigned short*)d_ws;        // 16384
  unsigned short* WoP   = WvP + 16384;                  // 131072
  unsigned short* attnP = WoP + 131072;                 // 10240
  float* qkP = (float*)(attnP + 10240);                 // 25600 floats

  hipLaunchKernelGGL(k_pre, dim3(290), dim3(256), 0, stream,
                     tf, Wq, bq, Wk, bk, Wv, Wo, WvP, WoP, qkP);
  hipLaunchKernelGGL(k_attn, dim3(8), dim3(256), 0, stream, qkP, attnP);

  hipFuncSetAttribute(reinterpret_cast<const void*>(&k_main),
                      hipFuncAttributeMaxDynamicSharedMemorySize, 75776);
  hipLaunchKernelGGL(k_main, dim3(4096), dim3(512), 75776, stream,
                     feature, bv, bo, WvP, WoP, attnP, out);
}